// Round 3
// baseline (381.870 us; speedup 1.0000x reference)
//
#include <hip/hip_runtime.h>

#define TS 524288u          // 2^19
#define PRIME 2654435761u
#define NPTS 1048576u
#define MASK (TS - 1u)

typedef float vfloat4 __attribute__((ext_vector_type(4)));

// floor(16 * fl32(g)^l), g = 64^(1/15); fl32(g) rounds UP so the exact-integer
// levels (5,10,15) floor to 64/256/1024 under correctly-rounded powf (= numpy).
__device__ __constant__ float c_scale[16] = {
    16.f, 21.f, 27.f, 36.f, 48.f, 64.f, 84.f, 111.f,
    147.f, 194.f, 256.f, 337.f, 445.f, 588.f, 776.f, 1024.f
};

// Staged levels 0-2 (res 16,21,27 -> grid widths 17,22,28).
// Level 3 (37^2 = ~86KB of lines per XCD) stays in L2 — dropping it from LDS
// cuts the block's LDS from 23.4KB to 12.2KB -> 8 blocks/CU (32 waves, was 24).
#define W0 17
#define W1 22
#define W2 28
#define B0 0
#define B1 (B0 + W0*W0)        // 289
#define B2 (B1 + W1*W1)        // 773
#define NSTAGE (B2 + W2*W2)    // 1557 float2 = 12456 B

__global__ __launch_bounds__(256) void hashenc_kernel(
    const float2* __restrict__ x,
    const float2* __restrict__ tab,
    vfloat4* __restrict__ out,
    unsigned pts_per_block)
{
    __shared__ float2 lds[NSTAGE];
    unsigned tid = threadIdx.x;

    // ---- Stage levels 0-2 into LDS (identical values to tab[hash(v)]) ----
#define STAGE(L, W, B)                                                  \
    for (unsigned i = tid; i < (unsigned)((W)*(W)); i += 256u) {        \
        unsigned vy = i / (unsigned)(W), vx = i % (unsigned)(W);        \
        unsigned h = ((vx ^ (vy * PRIME)) & MASK) | ((unsigned)(L) << 19); \
        lds[(B) + i] = tab[h];                                          \
    }
    STAGE(0, W0, B0)
    STAGE(1, W1, B1)
    STAGE(2, W2, B2)
#undef STAGE
    __syncthreads();

    const unsigned lq = tid & 3u;          // level quad: levels 4lq..4lq+3
    const unsigned lane_p = tid >> 2;      // 0..63: point slot within iteration
    const unsigned l0 = lq << 2;
    const unsigned bs = blockIdx.x * pts_per_block;
    unsigned be = bs + pts_per_block;
    if (be > NPTS) be = NPTS;

    const unsigned Wk[3] = { W0, W1, W2 };
    const unsigned Bk[3] = { B0, B1, B2 };

    for (unsigned p = bs + lane_p; p < be; p += 64u) {
        float2 xy = x[p];
        vfloat4 r[2];

        if (lq == 0u) {
            // ---- levels 0-2 from LDS, level 3 from global (L2-resident) ----
#pragma unroll
            for (int k = 0; k < 4; ++k) {
                float s = c_scale[k];
                float sx = xy.x * s, sy = xy.y * s;
                float fxf = floorf(sx), fyf = floorf(sy);
                float cxf = ceilf(sx),  cyf = ceilf(sy);
                float ox = sx - fxf, oy = sy - fyf;
                unsigned fx = (unsigned)(int)fxf, fy = (unsigned)(int)fyf;
                unsigned cx = (unsigned)(int)cxf, cy = (unsigned)(int)cyf;
                float2 f0, f1, f2, f3;
                if (k < 3) {
                    unsigned w = Wk[k], b = Bk[k];
                    f0 = lds[b + cy * w + cx];
                    f1 = lds[b + fy * w + cx];
                    f2 = lds[b + cy * w + fx];
                    f3 = lds[b + fy * w + fx];
                } else {
                    unsigned hcy = cy * PRIME, hfy = fy * PRIME;
                    unsigned base = 3u << 19;
                    f0 = tab[((cx ^ hcy) & MASK) | base];
                    f1 = tab[((cx ^ hfy) & MASK) | base];
                    f2 = tab[((fx ^ hcy) & MASK) | base];
                    f3 = tab[((fx ^ hfy) & MASK) | base];
                }
                float wox = 1.0f - ox, woy = 1.0f - oy;
                float f03x = f0.x * ox + f3.x * wox;
                float f03y = f0.y * ox + f3.y * wox;
                float f12x = f1.x * ox + f2.x * wox;
                float f12y = f1.y * ox + f2.y * wox;
                float ex = f03x * oy + f12x * woy;
                float ey = f03y * oy + f12y * woy;
                if ((k & 1) == 0) { r[k >> 1].x = ex; r[k >> 1].y = ey; }
                else              { r[k >> 1].z = ex; r[k >> 1].w = ey; }
            }
        } else {
            // ---- levels 4lq..4lq+3 from global (hashed gathers) ----
#pragma unroll
            for (int k = 0; k < 4; ++k) {
                unsigned l = l0 + (unsigned)k;
                float s = c_scale[l];
                float sx = xy.x * s, sy = xy.y * s;
                float fxf = floorf(sx), fyf = floorf(sy);
                float cxf = ceilf(sx),  cyf = ceilf(sy);
                float ox = sx - fxf, oy = sy - fyf;
                unsigned fx = (unsigned)(int)fxf, fy = (unsigned)(int)fyf;
                unsigned cx = (unsigned)(int)cxf, cy = (unsigned)(int)cyf;
                unsigned hcy = cy * PRIME, hfy = fy * PRIME;
                unsigned base = l << 19;
                float2 f0 = tab[((cx ^ hcy) & MASK) | base];
                float2 f1 = tab[((cx ^ hfy) & MASK) | base];
                float2 f2 = tab[((fx ^ hcy) & MASK) | base];
                float2 f3 = tab[((fx ^ hfy) & MASK) | base];
                float wox = 1.0f - ox, woy = 1.0f - oy;
                float f03x = f0.x * ox + f3.x * wox;
                float f03y = f0.y * ox + f3.y * wox;
                float f12x = f1.x * ox + f2.x * wox;
                float f12y = f1.y * ox + f2.y * wox;
                float ex = f03x * oy + f12x * woy;
                float ey = f03y * oy + f12y * woy;
                if ((k & 1) == 0) { r[k >> 1].x = ex; r[k >> 1].y = ey; }
                else              { r[k >> 1].z = ex; r[k >> 1].w = ey; }
            }
        }

        // out float4 index: p*8 + lq*2 (+1). Consecutive tid -> contiguous 32B
        // per thread, wave covers 2KB contiguous -> fully coalesced.
        unsigned o = p * 8u + lq * 2u;
        __builtin_nontemporal_store(r[0], &out[o]);
        __builtin_nontemporal_store(r[1], &out[o + 1]);
    }
}

extern "C" void kernel_launch(void* const* d_in, const int* in_sizes, int n_in,
                              void* d_out, int out_size, void* d_ws, size_t ws_size,
                              hipStream_t stream)
{
    const float2* x   = (const float2*)d_in[0];
    const float2* tab = (const float2*)d_in[1];
    vfloat4* out = (vfloat4*)d_out;

    const unsigned n_blocks = 2048u;                        // 8 blocks/CU (thread-capped)
    const unsigned ppb = (NPTS + n_blocks - 1u) / n_blocks; // 512
    hashenc_kernel<<<n_blocks, 256, 0, stream>>>(x, tab, out, ppb);
}